// Round 1
// baseline (2855.527 us; speedup 1.0000x reference)
//
#include <hip/hip_runtime.h>
#include <hip/hip_bf16.h>
#include <stdint.h>

#define T_TOK 16384
#define D_DIM 1024
#define E_NUM 8
#define H_DIM 2752
#define NSLOT (T_TOK * 2)   // total routed (token, expert) pairs = T * TOPK

typedef __bf16 bf16x8_t __attribute__((ext_vector_type(8)));
typedef float f32x4_t __attribute__((ext_vector_type(4)));

#define BM 128
#define BK 32
#define LDSP 40   // padded LDS k-stride (ushorts): breaks 8-way bank conflicts
#define BN1 64    // gemm1 N tile (43 * 64 = 2752 exact)
#define BN2 128   // gemm2 N tile (8 * 128 = 1024 exact)

__device__ __forceinline__ uint16_t f2bf(float f) {
    union { float f; uint32_t u; } v; v.f = f;
    uint32_t r = (v.u + 0x7FFFu + ((v.u >> 16) & 1u)) >> 16;  // RNE
    return (uint16_t)r;
}

__device__ __forceinline__ ushort4 f4_to_bf4(float4 v) {
    ushort4 r;
    r.x = f2bf(v.x); r.y = f2bf(v.y); r.z = f2bf(v.z); r.w = f2bf(v.w);
    return r;
}

// ---------------- router: fp64 logits, softmax top-2, normalized weights ----
__global__ void router_kernel(const float* __restrict__ x, const float* __restrict__ gw,
                              int* __restrict__ counts, int* __restrict__ topk_i,
                              float* __restrict__ topk_w) {
    int t = blockIdx.x;
    int lane = threadIdx.x;  // 64
    const float* xr = x + (size_t)t * D_DIM;
    double acc[E_NUM];
#pragma unroll
    for (int e = 0; e < E_NUM; ++e) acc[e] = 0.0;
    for (int k = lane; k < D_DIM; k += 64) {
        double xv = (double)xr[k];
#pragma unroll
        for (int e = 0; e < E_NUM; ++e) acc[e] += xv * (double)gw[e * D_DIM + k];
    }
#pragma unroll
    for (int e = 0; e < E_NUM; ++e) {
        double v = acc[e];
        for (int off = 32; off > 0; off >>= 1) v += __shfl_down(v, off, 64);
        acc[e] = v;
    }
    if (lane == 0) {
        int i0 = 0; double m0 = acc[0];
#pragma unroll
        for (int e = 1; e < E_NUM; ++e) if (acc[e] > m0) { m0 = acc[e]; i0 = e; }
        int i1 = -1; double m1 = -1.0e300;
#pragma unroll
        for (int e = 0; e < E_NUM; ++e) if (e != i0 && acc[e] > m1) { m1 = acc[e]; i1 = e; }
        double e1 = exp(m1 - m0);
        double s = 1.0 + e1;
        topk_i[t * 2 + 0] = i0; topk_i[t * 2 + 1] = i1;
        topk_w[t * 2 + 0] = (float)(1.0 / s);
        topk_w[t * 2 + 1] = (float)(e1 / s);
        atomicAdd(&counts[i0], 1);
        atomicAdd(&counts[i1], 1);
    }
}

__global__ void prefix_kernel(const int* __restrict__ counts, int* __restrict__ bases) {
    int s = 0;
    for (int e = 0; e < E_NUM; ++e) { bases[e] = s; s += counts[e]; }
}

// ---------------- gather: assign slots, copy x rows -> bf16 Xg --------------
__global__ void gather_kernel(const float* __restrict__ x, const int* __restrict__ topk_i,
                              const float* __restrict__ topk_w, const int* __restrict__ bases,
                              int* __restrict__ fills, int* __restrict__ slot_tok,
                              float* __restrict__ slot_w, uint16_t* __restrict__ Xg) {
    int t = blockIdx.x;
    int lane = threadIdx.x;  // 64
    int slot0 = 0, slot1 = 0;
    if (lane == 0) {
        int e0 = topk_i[t * 2 + 0], e1 = topk_i[t * 2 + 1];
        slot0 = bases[e0] + atomicAdd(&fills[e0], 1);
        slot1 = bases[e1] + atomicAdd(&fills[e1], 1);
        slot_tok[slot0] = t; slot_w[slot0] = topk_w[t * 2 + 0];
        slot_tok[slot1] = t; slot_w[slot1] = topk_w[t * 2 + 1];
    }
    slot0 = __shfl(slot0, 0, 64);
    slot1 = __shfl(slot1, 0, 64);
    const float4* xr = (const float4*)(x + (size_t)t * D_DIM);
    ushort4 a0 = f4_to_bf4(xr[lane * 4 + 0]);
    ushort4 a1 = f4_to_bf4(xr[lane * 4 + 1]);
    ushort4 a2 = f4_to_bf4(xr[lane * 4 + 2]);
    ushort4 a3 = f4_to_bf4(xr[lane * 4 + 3]);
    ushort4* d0 = (ushort4*)(Xg + (size_t)slot0 * D_DIM + lane * 16);
    ushort4* d1 = (ushort4*)(Xg + (size_t)slot1 * D_DIM + lane * 16);
    d0[0] = a0; d0[1] = a1; d0[2] = a2; d0[3] = a3;
    d1[0] = a0; d1[1] = a1; d1[2] = a2; d1[3] = a3;
}

// ---------------- gemm1: hidden = silu(Xe @ w1^T) * (Xe @ w3^T), bf16 out ---
__global__ __launch_bounds__(256) void gemm1_kernel(
    const uint16_t* __restrict__ Xg, const float* __restrict__ w1,
    const float* __restrict__ w3, const int* __restrict__ counts,
    const int* __restrict__ bases, uint16_t* __restrict__ hidden) {
    int e = blockIdx.z;
    int cnt = counts[e];
    int m0 = blockIdx.y * BM;
    if (m0 >= cnt) return;
    int n0 = blockIdx.x * BN1;
    int base = bases[e];

    __shared__ __align__(16) uint16_t As[BM * LDSP];
    __shared__ __align__(16) uint16_t B1s[BN1 * LDSP];
    __shared__ __align__(16) uint16_t B3s[BN1 * LDSP];

    int tid = threadIdx.x;
    int wave = tid >> 6, lane = tid & 63;
    int rA = lane & 15, kq = lane >> 4;

    const float* w1e = w1 + (size_t)e * H_DIM * D_DIM;
    const float* w3e = w3 + (size_t)e * H_DIM * D_DIM;

    f32x4_t acc1[2][4], acc3[2][4];
#pragma unroll
    for (int r = 0; r < 2; ++r)
#pragma unroll
        for (int n = 0; n < 4; ++n) {
            acc1[r][n] = (f32x4_t){0.f, 0.f, 0.f, 0.f};
            acc3[r][n] = (f32x4_t){0.f, 0.f, 0.f, 0.f};
        }

    for (int k0 = 0; k0 < D_DIM; k0 += BK) {
        __syncthreads();
        // stage A (bf16): 128 rows x 4 kgroups of 8 -> 512 chunks
        for (int c = tid; c < 512; c += 256) {
            int row = c >> 2, kg = c & 3;
            int gm = m0 + row;
            int slot = base + (gm < cnt ? gm : 0);
            *(uint4*)&As[row * LDSP + kg * 8] =
                *(const uint4*)(Xg + (size_t)slot * D_DIM + k0 + kg * 8);
        }
        // stage B1/B3 (fp32 -> bf16): 64 rows x 8 float4 -> 512 chunks
        for (int c = tid; c < 512; c += 256) {
            int n = c >> 3, j = c & 7;
            size_t off = (size_t)(n0 + n) * D_DIM + k0 + j * 4;
            *(ushort4*)&B1s[n * LDSP + j * 4] = f4_to_bf4(*(const float4*)(w1e + off));
            *(ushort4*)&B3s[n * LDSP + j * 4] = f4_to_bf4(*(const float4*)(w3e + off));
        }
        __syncthreads();

        bf16x8_t a0 = *(const bf16x8_t*)&As[(wave * 32 + 0 + rA) * LDSP + kq * 8];
        bf16x8_t a1 = *(const bf16x8_t*)&As[(wave * 32 + 16 + rA) * LDSP + kq * 8];
#pragma unroll
        for (int n = 0; n < 4; ++n) {
            bf16x8_t b1 = *(const bf16x8_t*)&B1s[(n * 16 + rA) * LDSP + kq * 8];
            bf16x8_t b3 = *(const bf16x8_t*)&B3s[(n * 16 + rA) * LDSP + kq * 8];
            acc1[0][n] = __builtin_amdgcn_mfma_f32_16x16x32_bf16(a0, b1, acc1[0][n], 0, 0, 0);
            acc1[1][n] = __builtin_amdgcn_mfma_f32_16x16x32_bf16(a1, b1, acc1[1][n], 0, 0, 0);
            acc3[0][n] = __builtin_amdgcn_mfma_f32_16x16x32_bf16(a0, b3, acc3[0][n], 0, 0, 0);
            acc3[1][n] = __builtin_amdgcn_mfma_f32_16x16x32_bf16(a1, b3, acc3[1][n], 0, 0, 0);
        }
    }

    // epilogue: h = silu(g1) * g3 -> bf16 hidden[base+m][n0+col]
#pragma unroll
    for (int r = 0; r < 2; ++r)
#pragma unroll
        for (int n = 0; n < 4; ++n)
#pragma unroll
            for (int i = 0; i < 4; ++i) {
                int mrow = m0 + wave * 32 + r * 16 + kq * 4 + i;
                if (mrow < cnt) {
                    float g = acc1[r][n][i];
                    float s = g / (1.0f + __expf(-g));
                    float h = s * acc3[r][n][i];
                    hidden[(size_t)(base + mrow) * H_DIM + n0 + n * 16 + rA] = f2bf(h);
                }
            }
}

// ---------------- gemm2: y[token] += w_slot * (hidden @ w2^T) ---------------
__global__ __launch_bounds__(256) void gemm2_kernel(
    const uint16_t* __restrict__ hidden, const float* __restrict__ w2,
    const int* __restrict__ counts, const int* __restrict__ bases,
    const int* __restrict__ slot_tok, const float* __restrict__ slot_w,
    float* __restrict__ out) {
    int e = blockIdx.z;
    int cnt = counts[e];
    int m0 = blockIdx.y * BM;
    if (m0 >= cnt) return;
    int d0 = blockIdx.x * BN2;
    int base = bases[e];

    __shared__ __align__(16) uint16_t As[BM * LDSP];
    __shared__ __align__(16) uint16_t Bs[BN2 * LDSP];

    int tid = threadIdx.x;
    int wave = tid >> 6, lane = tid & 63;
    int rA = lane & 15, kq = lane >> 4;
    const float* w2e = w2 + (size_t)e * D_DIM * H_DIM;

    f32x4_t acc[2][8];
#pragma unroll
    for (int r = 0; r < 2; ++r)
#pragma unroll
        for (int n = 0; n < 8; ++n) acc[r][n] = (f32x4_t){0.f, 0.f, 0.f, 0.f};

    for (int k0 = 0; k0 < H_DIM; k0 += BK) {  // 86 iterations
        __syncthreads();
        for (int c = tid; c < 512; c += 256) {
            int row = c >> 2, kg = c & 3;
            int gm = m0 + row;
            int slot = base + (gm < cnt ? gm : 0);
            *(uint4*)&As[row * LDSP + kg * 8] =
                *(const uint4*)(hidden + (size_t)slot * H_DIM + k0 + kg * 8);
        }
        for (int c = tid; c < 1024; c += 256) {
            int n = c >> 3, j = c & 7;
            size_t off = (size_t)(d0 + n) * H_DIM + k0 + j * 4;
            *(ushort4*)&Bs[n * LDSP + j * 4] = f4_to_bf4(*(const float4*)(w2e + off));
        }
        __syncthreads();

        bf16x8_t a0 = *(const bf16x8_t*)&As[(wave * 32 + 0 + rA) * LDSP + kq * 8];
        bf16x8_t a1 = *(const bf16x8_t*)&As[(wave * 32 + 16 + rA) * LDSP + kq * 8];
#pragma unroll
        for (int n = 0; n < 8; ++n) {
            bf16x8_t b = *(const bf16x8_t*)&Bs[(n * 16 + rA) * LDSP + kq * 8];
            acc[0][n] = __builtin_amdgcn_mfma_f32_16x16x32_bf16(a0, b, acc[0][n], 0, 0, 0);
            acc[1][n] = __builtin_amdgcn_mfma_f32_16x16x32_bf16(a1, b, acc[1][n], 0, 0, 0);
        }
    }

#pragma unroll
    for (int r = 0; r < 2; ++r)
#pragma unroll
        for (int i = 0; i < 4; ++i) {
            int mrow = m0 + wave * 32 + r * 16 + kq * 4 + i;
            if (mrow < cnt) {
                int slot = base + mrow;
                float w = slot_w[slot];
                int tok = slot_tok[slot];
                float* orow = out + (size_t)tok * D_DIM + d0;
#pragma unroll
                for (int n = 0; n < 8; ++n)
                    atomicAdd(&orow[n * 16 + rA], w * acc[r][n][i]);
            }
        }
}

// ---------------- launch ----------------------------------------------------
extern "C" void kernel_launch(void* const* d_in, const int* in_sizes, int n_in,
                              void* d_out, int out_size, void* d_ws, size_t ws_size,
                              hipStream_t stream) {
    const float* x  = (const float*)d_in[0];
    const float* gw = (const float*)d_in[1];
    const float* w1 = (const float*)d_in[2];
    const float* w2 = (const float*)d_in[3];
    const float* w3 = (const float*)d_in[4];
    float* out = (float*)d_out;
    char* ws = (char*)d_ws;

    int*   counts   = (int*)(ws + 0);
    int*   fills    = (int*)(ws + 64);
    int*   bases    = (int*)(ws + 128);
    int*   topk_i   = (int*)(ws + 256);
    float* topk_w   = (float*)(ws + 256 + 131072);
    int*   slot_tok = (int*)(ws + 256 + 2 * 131072);
    float* slot_w   = (float*)(ws + 256 + 3 * 131072);
    uint16_t* Xg     = (uint16_t*)(ws + (1 << 20));
    uint16_t* hidden = (uint16_t*)(ws + (1 << 20) + (size_t)NSLOT * D_DIM * 2);
    // total ws use: 1 MiB + 64 MiB (Xg) + 172 MiB (hidden) ~= 237 MiB

    hipMemsetAsync(ws, 0, 256, stream);                         // counts/fills
    hipMemsetAsync(d_out, 0, (size_t)out_size * 4, stream);     // y accumulator

    router_kernel<<<T_TOK, 64, 0, stream>>>(x, gw, counts, topk_i, topk_w);
    prefix_kernel<<<1, 1, 0, stream>>>(counts, bases);
    gather_kernel<<<T_TOK, 64, 0, stream>>>(x, topk_i, topk_w, bases, fills,
                                            slot_tok, slot_w, Xg);
    gemm1_kernel<<<dim3(H_DIM / BN1, T_TOK / BM, E_NUM), 256, 0, stream>>>(
        Xg, w1, w3, counts, bases, hidden);
    gemm2_kernel<<<dim3(D_DIM / BN2, T_TOK / BM, E_NUM), 256, 0, stream>>>(
        hidden, w2, counts, bases, slot_tok, slot_w, out);
}

// Round 3
// 1801.618 us; speedup vs baseline: 1.5850x; 1.5850x over previous
//
#include <hip/hip_runtime.h>
#include <hip/hip_bf16.h>
#include <stdint.h>

#define T_TOK 16384
#define D_DIM 1024
#define E_NUM 8
#define H_DIM 2752
#define NSLOT (T_TOK * 2)

typedef __bf16 bf16x8_t __attribute__((ext_vector_type(8)));
typedef float f32x4_t __attribute__((ext_vector_type(4)));

__device__ __forceinline__ uint16_t f2bf(float f) {
    union { float f; uint32_t u; } v; v.f = f;
    return (uint16_t)((v.u + 0x7FFFu + ((v.u >> 16) & 1u)) >> 16);  // RNE
}
__device__ __forceinline__ ushort4 f4_to_bf4(float4 v) {
    ushort4 r; r.x = f2bf(v.x); r.y = f2bf(v.y); r.z = f2bf(v.z); r.w = f2bf(v.w);
    return r;
}
// async global->LDS, 16B/lane; HW writes LDS at (wave-uniform base) + lane*16
__device__ __forceinline__ void gl_lds16(const uint16_t* g, uint16_t* l) {
    __builtin_amdgcn_global_load_lds((const __attribute__((address_space(1))) void*)g,
                                     (__attribute__((address_space(3))) void*)l,
                                     16, 0, 0);
}

// ---------------- router: fp64 logits, softmax top-2 ------------------------
__global__ void router_kernel(const float* __restrict__ x, const float* __restrict__ gw,
                              int* __restrict__ counts_f, int* __restrict__ counts_s,
                              int* __restrict__ topk_i, float* __restrict__ topk_w) {
    int t = blockIdx.x;
    int lane = threadIdx.x;  // 64
    const float* xr = x + (size_t)t * D_DIM;
    double acc[E_NUM];
#pragma unroll
    for (int e = 0; e < E_NUM; ++e) acc[e] = 0.0;
    for (int k = lane; k < D_DIM; k += 64) {
        double xv = (double)xr[k];
#pragma unroll
        for (int e = 0; e < E_NUM; ++e) acc[e] += xv * (double)gw[e * D_DIM + k];
    }
#pragma unroll
    for (int e = 0; e < E_NUM; ++e) {
        double v = acc[e];
        for (int off = 32; off > 0; off >>= 1) v += __shfl_down(v, off, 64);
        acc[e] = v;
    }
    if (lane == 0) {
        int i0 = 0; double m0 = acc[0];
#pragma unroll
        for (int e = 1; e < E_NUM; ++e) if (acc[e] > m0) { m0 = acc[e]; i0 = e; }
        int i1 = -1; double m1 = -1.0e300;
#pragma unroll
        for (int e = 0; e < E_NUM; ++e) if (e != i0 && acc[e] > m1) { m1 = acc[e]; i1 = e; }
        double e1 = exp(m1 - m0);
        double s = 1.0 + e1;
        topk_i[t * 2 + 0] = i0; topk_i[t * 2 + 1] = i1;
        topk_w[t * 2 + 0] = (float)(1.0 / s);
        topk_w[t * 2 + 1] = (float)(e1 / s);
        atomicAdd(&counts_f[i0], 1);   // t's top-1 expert
        atomicAdd(&counts_s[i1], 1);   // t's top-2 expert
    }
}

__global__ void prefix_kernel(const int* __restrict__ cf, const int* __restrict__ cs,
                              int* __restrict__ bases, int* __restrict__ splits,
                              int* __restrict__ cnts) {
    int s = 0;
    for (int e = 0; e < E_NUM; ++e) {
        bases[e] = s;
        splits[e] = s + cf[e];          // first-slot range: [base, split)
        cnts[e] = cf[e] + cs[e];        // second-slot range: [split, base+cnt)
        s += cnts[e];
    }
}

// ---------------- assign: token -> two slots (first/second sub-ranges) ------
__global__ __launch_bounds__(256) void assign_kernel(
    const int* __restrict__ topk_i, const float* __restrict__ topk_w,
    const int* __restrict__ bases, const int* __restrict__ splits,
    int* __restrict__ fills_f, int* __restrict__ fills_s,
    int* __restrict__ slot_tok, float* __restrict__ slot_w) {
    int t = blockIdx.x * 256 + threadIdx.x;
    int e0 = topk_i[t * 2 + 0], e1 = topk_i[t * 2 + 1];
    int s0 = bases[e0] + atomicAdd(&fills_f[e0], 1);
    int s1 = splits[e1] + atomicAdd(&fills_s[e1], 1);
    slot_tok[s0] = t; slot_w[s0] = topk_w[t * 2 + 0];
    slot_tok[s1] = t; slot_w[s1] = topk_w[t * 2 + 1];
}

// ---------------- converts --------------------------------------------------
__global__ __launch_bounds__(256) void cvtx_kernel(const float* __restrict__ x,
                                                   uint16_t* __restrict__ Xb) {
    size_t i = (size_t)blockIdx.x * 256 + threadIdx.x;  // 16384*256 float4s exact
    ((ushort4*)Xb)[i] = f4_to_bf4(((const float4*)x)[i]);
}
__global__ __launch_bounds__(256) void cvt13_kernel(const float* __restrict__ w1,
                                                    const float* __restrict__ w3,
                                                    uint16_t* __restrict__ w1be,
                                                    uint16_t* __restrict__ w3be, int e) {
    size_t i = (size_t)blockIdx.x * 256 + threadIdx.x;  // 2752*256 float4s exact
    const float4* s1 = (const float4*)(w1 + (size_t)e * H_DIM * D_DIM);
    const float4* s3 = (const float4*)(w3 + (size_t)e * H_DIM * D_DIM);
    ((ushort4*)w1be)[i] = f4_to_bf4(s1[i]);
    ((ushort4*)w3be)[i] = f4_to_bf4(s3[i]);
}
__global__ __launch_bounds__(256) void cvt2_kernel(const float* __restrict__ w2,
                                                   uint16_t* __restrict__ w2b) {
    size_t i = (size_t)blockIdx.x * 256 + threadIdx.x;  // 22016*256 float4s exact
    ((ushort4*)w2b)[i] = f4_to_bf4(((const float4*)w2)[i]);
}

// ---------------- gemm1 (one expert): hidden = silu(Xe@w1^T)*(Xe@w3^T) ------
// 128(M) x 64(N, dual B1/B3), BK=32; A rows via slot_tok indirection into Xb.
__global__ __launch_bounds__(256) void gemm1_kernel(
    const uint16_t* __restrict__ Xb, const uint16_t* __restrict__ w1be,
    const uint16_t* __restrict__ w3be, const int* __restrict__ slot_tok,
    const int* __restrict__ cnts, const int* __restrict__ bases,
    uint16_t* __restrict__ hidden, int e) {
    int cnt = cnts[e];
    int m0 = blockIdx.y * 128;
    if (m0 >= cnt) return;
    int n0 = blockIdx.x * 64;
    int base = bases[e];

    __shared__ __align__(16) uint16_t As[128 * 32];
    __shared__ __align__(16) uint16_t B1s[64 * 32];
    __shared__ __align__(16) uint16_t B3s[64 * 32];

    int tid = threadIdx.x;
    int w = tid >> 6, lane = tid & 63;
    int rA = lane & 15, kq = lane >> 4;
    int lr = lane >> 2, lc = lane & 3;  // staging: 16 rows x 4 chunks of 16B

    int tok0 = slot_tok[base + min(m0 + w * 32 + lr, cnt - 1)];
    int tok1 = slot_tok[base + min(m0 + w * 32 + 16 + lr, cnt - 1)];
    const uint16_t* pA0 = Xb + (size_t)tok0 * D_DIM + lc * 8;
    const uint16_t* pA1 = Xb + (size_t)tok1 * D_DIM + lc * 8;
    const uint16_t* pB1 = w1be + (size_t)(n0 + w * 16 + lr) * D_DIM + lc * 8;
    const uint16_t* pB3 = w3be + (size_t)(n0 + w * 16 + lr) * D_DIM + lc * 8;
    uint16_t* lA0 = &As[(w * 2 + 0) * 512];
    uint16_t* lA1 = &As[(w * 2 + 1) * 512];
    uint16_t* lB1 = &B1s[w * 512];
    uint16_t* lB3 = &B3s[w * 512];

    f32x4_t acc1[2][4], acc3[2][4];
#pragma unroll
    for (int r = 0; r < 2; ++r)
#pragma unroll
        for (int n = 0; n < 4; ++n) {
            acc1[r][n] = (f32x4_t){0.f, 0.f, 0.f, 0.f};
            acc3[r][n] = (f32x4_t){0.f, 0.f, 0.f, 0.f};
        }

    for (int k0 = 0; k0 < D_DIM; k0 += 32) {
        __syncthreads();
        gl_lds16(pA0, lA0);
        gl_lds16(pA1, lA1);
        gl_lds16(pB1, lB1);
        gl_lds16(pB3, lB3);
        pA0 += 32; pA1 += 32; pB1 += 32; pB3 += 32;
        __syncthreads();

        bf16x8_t a0 = *(const bf16x8_t*)&As[(w * 32 + rA) * 32 + kq * 8];
        bf16x8_t a1 = *(const bf16x8_t*)&As[(w * 32 + 16 + rA) * 32 + kq * 8];
#pragma unroll
        for (int n = 0; n < 4; ++n) {
            bf16x8_t b1 = *(const bf16x8_t*)&B1s[(n * 16 + rA) * 32 + kq * 8];
            bf16x8_t b3 = *(const bf16x8_t*)&B3s[(n * 16 + rA) * 32 + kq * 8];
            acc1[0][n] = __builtin_amdgcn_mfma_f32_16x16x32_bf16(a0, b1, acc1[0][n], 0, 0, 0);
            acc1[1][n] = __builtin_amdgcn_mfma_f32_16x16x32_bf16(a1, b1, acc1[1][n], 0, 0, 0);
            acc3[0][n] = __builtin_amdgcn_mfma_f32_16x16x32_bf16(a0, b3, acc3[0][n], 0, 0, 0);
            acc3[1][n] = __builtin_amdgcn_mfma_f32_16x16x32_bf16(a1, b3, acc3[1][n], 0, 0, 0);
        }
    }

#pragma unroll
    for (int r = 0; r < 2; ++r)
#pragma unroll
        for (int n = 0; n < 4; ++n)
#pragma unroll
            for (int i = 0; i < 4; ++i) {
                int mrow = m0 + w * 32 + r * 16 + kq * 4 + i;
                if (mrow < cnt) {
                    float g = acc1[r][n][i];
                    float s = g / (1.0f + __expf(-g));
                    float h = s * acc3[r][n][i];
                    hidden[(size_t)(base + mrow) * H_DIM + n0 + n * 16 + rA] = f2bf(h);
                }
            }
}

// ---------------- gemm2: out[tok] (store / +=) = w_slot * (hidden @ w2^T) ---
// pass 0: first-slot rows, plain store (covers every token exactly once).
// pass 1: second-slot rows, read-add-write. Passes serialized by stream.
__global__ __launch_bounds__(256) void gemm2_kernel(
    const uint16_t* __restrict__ hidden, const uint16_t* __restrict__ w2b,
    const int* __restrict__ cnts, const int* __restrict__ bases,
    const int* __restrict__ splits, const int* __restrict__ slot_tok,
    const float* __restrict__ slot_w, float* __restrict__ out, int pass) {
    int e = blockIdx.z;
    int cnt = cnts[e];
    int m0 = blockIdx.y * 128;
    if (m0 >= cnt) return;
    int base = bases[e];
    int split = splits[e];
    if (pass == 0 && base + m0 >= split) return;          // tile entirely second
    if (pass == 1 && base + m0 + 128 <= split) return;    // tile entirely first
    int d0 = blockIdx.x * 128;

    __shared__ __align__(16) uint16_t As[128 * 32];
    __shared__ __align__(16) uint16_t Bs[128 * 32];

    int tid = threadIdx.x;
    int w = tid >> 6, lane = tid & 63;
    int rA = lane & 15, kq = lane >> 4;
    int lr = lane >> 2, lc = lane & 3;
    int mh = w & 1, nh = w >> 1;

    int sl0 = base + min(m0 + w * 32 + lr, cnt - 1);
    int sl1 = base + min(m0 + w * 32 + 16 + lr, cnt - 1);
    const uint16_t* pA0 = hidden + (size_t)sl0 * H_DIM + lc * 8;
    const uint16_t* pA1 = hidden + (size_t)sl1 * H_DIM + lc * 8;
    const uint16_t* pB0 = w2b + (size_t)(e * D_DIM + d0 + w * 32 + lr) * H_DIM + lc * 8;
    const uint16_t* pB1 = w2b + (size_t)(e * D_DIM + d0 + w * 32 + 16 + lr) * H_DIM + lc * 8;
    uint16_t* lA0 = &As[(w * 2 + 0) * 512];
    uint16_t* lA1 = &As[(w * 2 + 1) * 512];
    uint16_t* lB0 = &Bs[(w * 2 + 0) * 512];
    uint16_t* lB1 = &Bs[(w * 2 + 1) * 512];

    f32x4_t acc[4][4];
#pragma unroll
    for (int mf = 0; mf < 4; ++mf)
#pragma unroll
        for (int nf = 0; nf < 4; ++nf) acc[mf][nf] = (f32x4_t){0.f, 0.f, 0.f, 0.f};

    for (int k0 = 0; k0 < H_DIM; k0 += 32) {  // 86 steps
        __syncthreads();
        gl_lds16(pA0, lA0);
        gl_lds16(pA1, lA1);
        gl_lds16(pB0, lB0);
        gl_lds16(pB1, lB1);
        pA0 += 32; pA1 += 32; pB0 += 32; pB1 += 32;
        __syncthreads();

        bf16x8_t a[4], b[4];
#pragma unroll
        for (int mf = 0; mf < 4; ++mf)
            a[mf] = *(const bf16x8_t*)&As[(mh * 64 + mf * 16 + rA) * 32 + kq * 8];
#pragma unroll
        for (int nf = 0; nf < 4; ++nf)
            b[nf] = *(const bf16x8_t*)&Bs[(nh * 64 + nf * 16 + rA) * 32 + kq * 8];
#pragma unroll
        for (int mf = 0; mf < 4; ++mf)
#pragma unroll
            for (int nf = 0; nf < 4; ++nf)
                acc[mf][nf] = __builtin_amdgcn_mfma_f32_16x16x32_bf16(a[mf], b[nf], acc[mf][nf], 0, 0, 0);
    }

#pragma unroll
    for (int mf = 0; mf < 4; ++mf)
#pragma unroll
        for (int i = 0; i < 4; ++i) {
            int mr = m0 + mh * 64 + mf * 16 + kq * 4 + i;
            if (mr < cnt) {
                int slot = base + mr;
                bool isfirst = slot < split;
                if ((pass == 0) == isfirst) {
                    float wgt = slot_w[slot];
                    int tok = slot_tok[slot];
                    float* yr = out + (size_t)tok * D_DIM + d0 + nh * 64;
                    if (pass == 0) {
#pragma unroll
                        for (int nf = 0; nf < 4; ++nf)
                            yr[nf * 16 + rA] = wgt * acc[mf][nf][i];
                    } else {
#pragma unroll
                        for (int nf = 0; nf < 4; ++nf)
                            yr[nf * 16 + rA] += wgt * acc[mf][nf][i];
                    }
                }
            }
        }
}

// ---------------- launch ----------------------------------------------------
extern "C" void kernel_launch(void* const* d_in, const int* in_sizes, int n_in,
                              void* d_out, int out_size, void* d_ws, size_t ws_size,
                              hipStream_t stream) {
    const float* x  = (const float*)d_in[0];
    const float* gw = (const float*)d_in[1];
    const float* w1 = (const float*)d_in[2];
    const float* w2 = (const float*)d_in[3];
    const float* w3 = (const float*)d_in[4];
    float* out = (float*)d_out;
    char* ws = (char*)d_ws;

    // meta (first 4 MiB)
    int*   counts_f = (int*)(ws + 0);
    int*   counts_s = (int*)(ws + 32);
    int*   fills_f  = (int*)(ws + 64);
    int*   fills_s  = (int*)(ws + 96);
    int*   bases    = (int*)(ws + 128);
    int*   splits   = (int*)(ws + 160);
    int*   cnts     = (int*)(ws + 192);
    int*   topk_i   = (int*)(ws + 4096);
    float* topk_w   = (float*)(ws + 4096 + 1 * 131072);
    int*   slot_tok = (int*)(ws + 4096 + 2 * 131072);
    float* slot_w   = (float*)(ws + 4096 + 3 * 131072);

    // big regions (total ws use = 229,638,144 B ~= 219 MiB, < proven 245 MB):
    //   hidden @ 4 MiB : 32768*2752*2 = 180,355,072
    //   W region (45,088,768) @ hidden end:
    //     gemm1 phase: [w1be 5.63MB][w3be 5.63MB][Xb 33.55MB]
    //     gemm2 phase: [w2b 45.09MB]  (w13/Xb dead after gemm1)
    const size_t HID_OFF = 4ull << 20;
    const size_t W_OFF   = HID_OFF + (size_t)NSLOT * H_DIM * 2;
    const size_t W1SZ    = (size_t)H_DIM * D_DIM * 2;
    uint16_t* hidden = (uint16_t*)(ws + HID_OFF);
    uint16_t* w1be   = (uint16_t*)(ws + W_OFF);
    uint16_t* w3be   = (uint16_t*)(ws + W_OFF + W1SZ);
    uint16_t* Xb     = (uint16_t*)(ws + W_OFF + 2 * W1SZ);
    uint16_t* w2b    = (uint16_t*)(ws + W_OFF);

    hipMemsetAsync(ws, 0, 256, stream);  // counts/fills

    router_kernel<<<T_TOK, 64, 0, stream>>>(x, gw, counts_f, counts_s, topk_i, topk_w);
    prefix_kernel<<<1, 1, 0, stream>>>(counts_f, counts_s, bases, splits, cnts);
    assign_kernel<<<T_TOK / 256, 256, 0, stream>>>(topk_i, topk_w, bases, splits,
                                                   fills_f, fills_s, slot_tok, slot_w);
    cvtx_kernel<<<T_TOK * D_DIM / 1024, 256, 0, stream>>>(x, Xb);

    for (int e = 0; e < E_NUM; ++e) {
        cvt13_kernel<<<H_DIM, 256, 0, stream>>>(w1, w3, w1be, w3be, e);
        gemm1_kernel<<<dim3(H_DIM / 64, 128), 256, 0, stream>>>(
            Xb, w1be, w3be, slot_tok, cnts, bases, hidden, e);
    }

    cvt2_kernel<<<E_NUM * D_DIM * H_DIM / 1024, 256, 0, stream>>>(w2, w2b);
    gemm2_kernel<<<dim3(D_DIM / 128, 128, E_NUM), 256, 0, stream>>>(
        hidden, w2b, cnts, bases, splits, slot_tok, slot_w, out, 0);
    gemm2_kernel<<<dim3(D_DIM / 128, 128, E_NUM), 256, 0, stream>>>(
        hidden, w2b, cnts, bases, splits, slot_tok, slot_w, out, 1);
}